// Round 8
// baseline (507.506 us; speedup 1.0000x reference)
//
#include <hip/hip_runtime.h>
#include <hip/hip_bf16.h>
#include <math.h>

// x [64,3,224,224] fp32; expert: conv3x3 s2 (3->64)+ReLU -> conv3x3 s2 (64->128)
// +ReLU -> GAP -> FC 128->2; blend on t softmax conf <= 0.9. Out: 129 floats.
// SAME s2: pad_lo=0, pad_hi=1 both convs.
//
// Round-8: conv1+conv2 fused through LDS (h1 never touches HBM; saves the
// 209 MB write + ~260 MB read round-trip that bounded R7). conv1 weights via
// wave-uniform scalar loads; conv2 = R5's validated MFMA structure, K-split
// into two 32-ic chunks so the 5-row h1 tile fits in 45 KB LDS.
//
// ws layout (bytes):
//   W2B_OFF: ushort w2frag[2 term][2 e][8 octile][18 kc][64 lane][8]
//            oc = octile*16 + (lane&15); kk = kc*32 + (lane>>4)*8 + j
//            kk = kh*192 + kw*64 + ic ; kc = kh*6 + kw*2 + icc
//   W1T_OFF: float  w1t[2 e][27 k][64 ch]   k = ic*9+kh*3+kw
//   G_OFF:   float  g[2 e][64 b][128 oc]

#define W2B_OFF   0ull
#define W1T_OFF   589824ull
#define G_OFF     603648ull
#define WS_NEED   669440ull

typedef __attribute__((ext_vector_type(8))) short bf16x8;
typedef __attribute__((ext_vector_type(4))) float f32x4;

__device__ inline ushort f2bf(float v) {
  __hip_bfloat16 h = __float2bfloat16(v);
  return *(ushort*)&h;
}
__device__ inline float bf2f(ushort u) {
  __hip_bfloat16 h = *(__hip_bfloat16*)&u;
  return __bfloat162float(h);
}

__global__ __launch_bounds__(256) void prep_new(
    const float* __restrict__ w2_t, const float* __restrict__ w2_f,
    const float* __restrict__ w1_t, const float* __restrict__ w1_f,
    char* __restrict__ ws) {
  int idx = blockIdx.x * 256 + threadIdx.x;
  ushort* w2frag = (ushort*)(ws + W2B_OFF);
  float* w1t = (float*)(ws + W1T_OFF);
  if (idx < 294912) {
    int j    = idx & 7;
    int lane = (idx >> 3) & 63;
    int t2   = idx >> 9;          // [0,576)
    int kc   = t2 % 18;
    int t3   = t2 / 18;           // [0,32)
    int octile = t3 & 7;
    int t4   = t3 >> 3;           // [0,4)
    int e    = t4 & 1;
    int term = t4 >> 1;
    int oc = octile * 16 + (lane & 15);
    int kk = kc * 32 + (lane >> 4) * 8 + j;
    int kh = kk / 192, r2 = kk - kh * 192, kw = r2 >> 6, ic = r2 & 63;
    const float* src = e ? w2_f : w2_t;
    float w = src[((oc * 64 + ic) * 3 + kh) * 3 + kw];
    ushort hi = f2bf(w);
    w2frag[idx] = term ? f2bf(w - bf2f(hi)) : hi;
  } else if (idx < 294912 + 3456) {
    int i2 = idx - 294912;
    int e = i2 / 1728;
    int r = i2 - e * 1728;
    int k = r >> 6, ch = r & 63;
    const float* src = e ? w1_f : w1_t;
    w1t[i2] = src[ch * 27 + k];
  }
}

// Fused conv1->conv2. Block (T=out-row-pair 0..27, b, e), 256 thr = 4 waves.
// h1 tile: local rows 0..4 = global h1 rows 4T..4T+4, 113 hx, 32 ic per chunk,
// bf16 in LDS, row stride 40 shorts (80 B, 16B-aligned; banks ~4-way max).
// conv1: wave wv computes ch chunk*32+8wv..+7; lane -> hx {2*lane, 2*lane+1}.
// conv2: R5 wave layout: wv -> octiles {2wv,2wv+1}; 7 N-tiles (8px x 2rows).
__global__ __launch_bounds__(256, 3) void fused_conv(
    const float* __restrict__ x,
    const float* __restrict__ w1t_all,
    const float* __restrict__ b1_t, const float* __restrict__ b1_f,
    const ushort* __restrict__ w2frag,
    const float* __restrict__ b2_t, const float* __restrict__ b2_f,
    float* __restrict__ g)
{
  const int T = blockIdx.x;
  const int b = blockIdx.y;
  const int e = blockIdx.z;
  const int tid  = threadIdx.x;
  const int lane = tid & 63;
  const int wv   = __builtin_amdgcn_readfirstlane(tid >> 6);

  __shared__ ushort h1c[5 * 113 * 40];   // 45.2 KB

  const float* w1e = w1t_all + e * 1728;
  const float* b1  = e ? b1_f : b1_t;
  const float* b2  = e ? b2_f : b2_t;
  const float* xb  = x + (size_t)b * 150528;

  // MFMA lane ids (identical to validated R5 layout)
  const int q   = lane >> 4;
  const int n   = lane & 15;
  const int pxl = lane & 7;
  const int rl  = (lane >> 3) & 1;

  f32x4 acc[2][7];
#pragma unroll
  for (int mt = 0; mt < 2; ++mt)
#pragma unroll
    for (int nt = 0; nt < 7; ++nt) acc[mt][nt] = (f32x4){0.f, 0.f, 0.f, 0.f};

  const int hx0 = 2 * lane;            // conv1 px pair {hx0, hx0+1}

  for (int chunk = 0; chunk < 2; ++chunk) {
    if (chunk) __syncthreads();        // conv2(chunk 0) done reading h1c
    // ---------------- conv1: fill h1c for this ic-chunk ----------------
    const int ch0 = chunk * 32 + wv * 8;    // wave-uniform
    float bias[8];
#pragma unroll
    for (int c = 0; c < 8; ++c) bias[c] = b1[ch0 + c];

    for (int rg = 0; rg < 2; ++rg) {
      const int r0 = rg ? 3 : 0;
      const int nR = rg ? 2 : 3;
      float a1[3][2][8];
#pragma unroll
      for (int rr = 0; rr < 3; ++rr)
#pragma unroll
        for (int j = 0; j < 2; ++j)
#pragma unroll
          for (int c = 0; c < 8; ++c) a1[rr][j][c] = 0.f;

      if (lane < 56) {
#pragma unroll
        for (int ic = 0; ic < 3; ++ic) {
#pragma unroll
          for (int kr = 0; kr < 3; ++kr) {
            const float* wp = w1e + (ic * 9 + kr * 3) * 64 + ch0;  // uniform
            float w0[8], w1r[8], w2r[8];
#pragma unroll
            for (int c = 0; c < 8; ++c) {
              w0[c]  = wp[c];
              w1r[c] = wp[64 + c];
              w2r[c] = wp[128 + c];
            }
#pragma unroll
            for (int rr = 0; rr < 3; ++rr) {
              if (rr < nR) {
                const int row = 4 * T + r0 + rr;
                const int xr = 2 * row + kr;
                if (row < 112 && xr < 224) {
                  const float* xp = xb + (ic * 224 + xr) * 224 + 4 * lane;
                  const float4 x4 = *(const float4*)xp;
                  const float x5 = (lane < 55) ? xp[4] : 0.f;
                  const float xv[5] = {x4.x, x4.y, x4.z, x4.w, x5};
#pragma unroll
                  for (int j = 0; j < 2; ++j)
#pragma unroll
                    for (int c = 0; c < 8; ++c) {
                      float t = fmaf(w2r[c], xv[2 * j + 2], a1[rr][j][c]);
                      t = fmaf(w1r[c], xv[2 * j + 1], t);
                      a1[rr][j][c] = fmaf(w0[c], xv[2 * j], t);
                    }
                }
              }
            }
          }
        }
      }
      // store (+bias, ReLU, bf16) — pad entries exact zero
#pragma unroll
      for (int rr = 0; rr < 3; ++rr) {
        if (rr < nR) {
          const int rloc = r0 + rr;
          const bool live_row = (4 * T + rloc) < 112;
          if (lane < 56) {
#pragma unroll
            for (int j = 0; j < 2; ++j) {
              ushort v[8];
#pragma unroll
              for (int c = 0; c < 8; ++c)
                v[c] = f2bf(live_row ? fmaxf(a1[rr][j][c] + bias[c], 0.f) : 0.f);
              *(bf16x8*)&h1c[(rloc * 113 + hx0 + j) * 40 + 8 * wv] = *(bf16x8*)v;
            }
          } else if (lane == 56) {
            bf16x8 z = 0;   // hx = 112 pad column
            *(bf16x8*)&h1c[(rloc * 113 + 112) * 40 + 8 * wv] = z;
          }
        }
      }
    }
    __syncthreads();
    // ---------------- conv2: MFMA K-pass over this chunk ----------------
#pragma unroll
    for (int kh = 0; kh < 3; ++kh) {
#pragma unroll
      for (int kw = 0; kw < 3; ++kw) {
        const int kc = kh * 6 + kw * 2 + chunk;
        const int rloc = 2 * rl + kh;
        bf16x8 bfv[7];
#pragma unroll
        for (int nt = 0; nt < 7; ++nt) {
          const int hx = 2 * (8 * nt + pxl) + kw;
          bfv[nt] = *(const bf16x8*)&h1c[(rloc * 113 + hx) * 40 + 8 * q];
        }
#pragma unroll
        for (int term = 0; term < 2; ++term) {
#pragma unroll
          for (int mt = 0; mt < 2; ++mt) {
            const int octile = 2 * wv + mt;
            bf16x8 af = *(const bf16x8*)
                &w2frag[((size_t)(((term * 2 + e) * 8 + octile) * 18 + kc)) * 512
                        + lane * 8];
#pragma unroll
            for (int nt = 0; nt < 7; ++nt)
              acc[mt][nt] = __builtin_amdgcn_mfma_f32_16x16x32_bf16(
                  af, bfv[nt], acc[mt][nt], 0, 0, 0);
          }
        }
      }
    }
  }

  // ---- epilogue: +b2, ReLU, sum 112 px, shuffle-reduce, atomic into g ----
#pragma unroll
  for (int mt = 0; mt < 2; ++mt) {
#pragma unroll
    for (int reg = 0; reg < 4; ++reg) {
      const int oc = 32 * wv + 16 * mt + 4 * q + reg;
      const float bias2 = b2[oc];
      float s = 0.f;
#pragma unroll
      for (int nt = 0; nt < 7; ++nt) s += fmaxf(acc[mt][nt][reg] + bias2, 0.f);
      s += __shfl_xor(s, 1);
      s += __shfl_xor(s, 2);
      s += __shfl_xor(s, 4);
      s += __shfl_xor(s, 8);
      if (n == 0) atomicAdd(&g[((size_t)e * 64 + b) * 128 + oc], s);
    }
  }
}

__global__ __launch_bounds__(64) void finale(
    const float* __restrict__ g,
    const float* __restrict__ t_wf, const float* __restrict__ t_bf,
    const float* __restrict__ f_wf, const float* __restrict__ f_bf,
    float* __restrict__ out)
{
  const int b = threadIdx.x;
  const float inv = 1.0f / 3136.0f;
  const float* gt = g + b * 128;
  const float* gf = g + (64 + b) * 128;
  float lt0 = t_bf[0], lt1 = t_bf[1];
  float lf0 = f_bf[0], lf1 = f_bf[1];
  for (int k = 0; k < 128; ++k) {
    float vt = gt[k] * inv;
    float vf = gf[k] * inv;
    lt0 = fmaf(vt, t_wf[2 * k],     lt0);
    lt1 = fmaf(vt, t_wf[2 * k + 1], lt1);
    lf0 = fmaf(vf, f_wf[2 * k],     lf0);
    lf1 = fmaf(vf, f_wf[2 * k + 1], lf1);
  }
  float m  = fmaxf(lt0, lt1);
  float e0 = expf(lt0 - m), e1 = expf(lt1 - m);
  float conf = fmaxf(e0, e1) / (e0 + e1);
  bool use2 = (conf <= 0.9f);
  out[2 * b]     = use2 ? 0.7f * lt0 + 0.3f * lf0 : lt0;
  out[2 * b + 1] = use2 ? 0.7f * lt1 + 0.3f * lf1 : lt1;
  unsigned long long mask = __ballot(use2);
  if (b == 0) out[128] = (float)__popcll(mask) * (1.0f / 64.0f);
}

// ---------------- fallback (ws too small): round-1 fused fp32 ----------------
__global__ __launch_bounds__(256) void transpose_w2(
    const float* __restrict__ w2_t, const float* __restrict__ w2_f,
    float* __restrict__ w2t) {
  int idx = blockIdx.x * 256 + threadIdx.x;
  int e = idx / 73728;
  int r = idx - e * 73728;
  int k = r >> 7, oc = r & 127;
  const float* src = e ? w2_f : w2_t;
  w2t[idx] = src[oc * 576 + k];
}

__global__ __launch_bounds__(256, 3) void fused_expert(
    const float* __restrict__ x,
    const float* __restrict__ w1_t, const float* __restrict__ b1_t,
    const float* __restrict__ b2_t,
    const float* __restrict__ w1_f, const float* __restrict__ b1_f,
    const float* __restrict__ b2_f,
    const float* __restrict__ w2t_all, float* __restrict__ g)
{
  const int tile = blockIdx.x, b = blockIdx.y, e = blockIdx.z;
  const int ty = tile >> 1, tx = tile & 1;
  const float* w1  = e ? w1_f : w1_t;
  const float* b1  = e ? b1_f : b1_t;
  const float* b2  = e ? b2_f : b2_t;
  const float* w2t = w2t_all + e * 73728;
  __shared__ float x_s[3 * 19 * 116];
  __shared__ float h1_s[8 * 9 * 58];
  __shared__ float w1_s[1728];
  const int tid = threadIdx.x;
  {
    const float* xb = x + (size_t)b * 150528;
    const int xr0 = ty * 16, xc0 = tx * 112;
    for (int idx = tid; idx < 3 * 19 * 116; idx += 256) {
      int ic = idx / (19 * 116);
      int rem = idx - ic * (19 * 116);
      int r = rem / 116, cc = rem - r * 116;
      int xr = xr0 + r, xc = xc0 + cc;
      float v = 0.f;
      if (xr < 224 && xc < 224 && cc < 115) v = xb[(ic * 224 + xr) * 224 + xc];
      x_s[idx] = v;
    }
    for (int idx = tid; idx < 1728; idx += 256) w1_s[idx] = w1[idx];
  }
  const int ocg = tid >> 4, posg = tid & 15;
  int pbase[7];
#pragma unroll
  for (int j = 0; j < 7; ++j) {
    int p = posg + 16 * j, py = p / 28, px = p - py * 28;
    pbase[j] = py * 2 * 58 + px * 2;
  }
  float acc[7][8];
#pragma unroll
  for (int j = 0; j < 7; ++j)
#pragma unroll
    for (int i = 0; i < 8; ++i) acc[j][i] = 0.f;
  const int hc_l = tid >> 5, l32 = tid & 31;
  for (int c = 0; c < 8; ++c) {
    __syncthreads();
    {
      const int hc = c * 8 + hc_l;
      const float bias = b1[hc];
      float wr[27];
#pragma unroll
      for (int qq = 0; qq < 27; ++qq) wr[qq] = w1_s[hc * 27 + qq];
      for (int p = l32; p < 513; p += 32) {
        int hy = p / 57, hx = p - hy * 57;
        float a = bias;
#pragma unroll
        for (int ic = 0; ic < 3; ++ic)
#pragma unroll
          for (int kh = 0; kh < 3; ++kh) {
            const float* row = &x_s[ic * (19 * 116) + (2 * hy + kh) * 116 + 2 * hx];
            a = fmaf(row[0], wr[ic * 9 + kh * 3 + 0], a);
            a = fmaf(row[1], wr[ic * 9 + kh * 3 + 1], a);
            a = fmaf(row[2], wr[ic * 9 + kh * 3 + 2], a);
          }
        float v = fmaxf(a, 0.f);
        int hy_g = ty * 8 + hy, hx_g = tx * 56 + hx;
        if (hy_g >= 112 || hx_g >= 112) v = 0.f;
        h1_s[hc_l * 522 + hy * 58 + hx] = v;
      }
    }
    __syncthreads();
    for (int ic_l = 0; ic_l < 8; ++ic_l) {
#pragma unroll
      for (int kh = 0; kh < 3; ++kh)
#pragma unroll
        for (int kw = 0; kw < 3; ++kw) {
          const int k = (c * 8 + ic_l) * 9 + kh * 3 + kw;
          const float4 wA = *(const float4*)(w2t + k * 128 + ocg * 8);
          const float4 wB = *(const float4*)(w2t + k * 128 + ocg * 8 + 4);
          const float* hp = &h1_s[ic_l * 522 + kh * 58 + kw];
#pragma unroll
          for (int j = 0; j < 7; ++j) {
            float h = hp[pbase[j]];
            acc[j][0] = fmaf(wA.x, h, acc[j][0]);
            acc[j][1] = fmaf(wA.y, h, acc[j][1]);
            acc[j][2] = fmaf(wA.z, h, acc[j][2]);
            acc[j][3] = fmaf(wA.w, h, acc[j][3]);
            acc[j][4] = fmaf(wB.x, h, acc[j][4]);
            acc[j][5] = fmaf(wB.y, h, acc[j][5]);
            acc[j][6] = fmaf(wB.z, h, acc[j][6]);
            acc[j][7] = fmaf(wB.w, h, acc[j][7]);
          }
        }
    }
  }
  __syncthreads();
  float* red = x_s;
#pragma unroll
  for (int i = 0; i < 8; ++i) {
    float bb = b2[ocg * 8 + i];
    float t = 0.f;
#pragma unroll
    for (int j = 0; j < 7; ++j) t += fmaxf(acc[j][i] + bb, 0.f);
    red[posg * 129 + ocg * 8 + i] = t;
  }
  __syncthreads();
  if (tid < 128) {
    float t = 0.f;
#pragma unroll
    for (int pg = 0; pg < 16; ++pg) t += red[pg * 129 + tid];
    atomicAdd(&g[(e * 64 + b) * 128 + tid], t);
  }
}

extern "C" void kernel_launch(void* const* d_in, const int* in_sizes, int n_in,
                              void* d_out, int out_size, void* d_ws, size_t ws_size,
                              hipStream_t stream) {
  const float* x    = (const float*)d_in[0];
  const float* t_w1 = (const float*)d_in[1];
  const float* t_b1 = (const float*)d_in[2];
  const float* t_w2 = (const float*)d_in[3];
  const float* t_b2 = (const float*)d_in[4];
  const float* t_wf = (const float*)d_in[5];
  const float* t_bf = (const float*)d_in[6];
  const float* f_w1 = (const float*)d_in[7];
  const float* f_b1 = (const float*)d_in[8];
  const float* f_w2 = (const float*)d_in[9];
  const float* f_b2 = (const float*)d_in[10];
  const float* f_wf = (const float*)d_in[11];
  const float* f_bf = (const float*)d_in[12];
  float* out = (float*)d_out;
  char* ws = (char*)d_ws;

  if (ws_size >= WS_NEED) {
    float*  gbuf   = (float*)(ws + G_OFF);
    ushort* w2frag = (ushort*)(ws + W2B_OFF);
    float*  w1t    = (float*)(ws + W1T_OFF);
    hipMemsetAsync(gbuf, 0, 2 * 64 * 128 * sizeof(float), stream);
    prep_new<<<1166, 256, 0, stream>>>(t_w2, f_w2, t_w1, f_w1, ws);
    fused_conv<<<dim3(28, 64, 2), 256, 0, stream>>>(
        x, w1t, t_b1, f_b1, w2frag, t_b2, f_b2, gbuf);
    finale<<<1, 64, 0, stream>>>(gbuf, t_wf, t_bf, f_wf, f_bf, out);
  } else {
    float* w2t = (float*)ws;
    float* g2  = (float*)(ws + 589824);
    hipMemsetAsync(g2, 0, 2 * 64 * 128 * sizeof(float), stream);
    transpose_w2<<<576, 256, 0, stream>>>(t_w2, f_w2, w2t);
    fused_expert<<<dim3(28, 64, 2), 256, 0, stream>>>(
        x, t_w1, t_b1, t_b2, f_w1, f_b1, f_b2, w2t, g2);
    finale<<<1, 64, 0, stream>>>(g2, t_wf, t_bf, f_wf, f_bf, out);
  }
}

// Round 9
// 463.288 us; speedup vs baseline: 1.0954x; 1.0954x over previous
//
#include <hip/hip_runtime.h>
#include <hip/hip_bf16.h>
#include <math.h>

// x [64,3,224,224] fp32; expert: conv3x3 s2 (3->64)+ReLU -> conv3x3 s2 (64->128)
// +ReLU -> GAP -> FC 128->2; blend on t softmax conf <= 0.9. Out: 129 floats.
// SAME s2: pad_lo=0, pad_hi=1 both convs.
//
// Round-9: R7 structure (separate conv1/conv2; R8's intra-block fusion
// serialized the pipes and regressed). conv2 now LDS-free: B-fragments are
// contiguous 16B in the channel-last h1 layout, so read them directly from
// global; A from the L2-hot pre-swizzled w2frag. No __syncthreads in the
// K-loop at all -> no barrier drains.
//
// ws layout (bytes):
//   W2B_OFF: ushort w2frag[2 term][2 e][8 octile][18 kc][64 lane][8]
//            oc = octile*16 + (lane&15); kk = kc*32 + (lane>>4)*8 + j
//            kk = kh*192 + kw*64 + ic ; kc = kh*6 + kw*2 + icc
//   W1T_OFF: float  w1t[2 e][27 k][64 ch]   k = ic*9+kh*3+kw
//   G_OFF:   float  g[2 e][64 b][128 oc]
//   H1_OFF:  ushort h1[2 e][64 b][113 row][113 hx][64 ic] (row/col 112 = 0)

#define W2B_OFF   0ull
#define W1T_OFF   589824ull
#define G_OFF     603648ull
#define H1_OFF    669440ull
#define H1E_US    52301824ull   // 64*113*113*64
#define H1B_US    817216ull     // 113*113*64
#define WS_NEED   (H1_OFF + 2ull*H1E_US*2ull + 4096ull)

typedef __attribute__((ext_vector_type(8))) short bf16x8;
typedef __attribute__((ext_vector_type(4))) float f32x4;

__device__ inline ushort f2bf(float v) {
  __hip_bfloat16 h = __float2bfloat16(v);
  return *(ushort*)&h;
}
__device__ inline float bf2f(ushort u) {
  __hip_bfloat16 h = *(__hip_bfloat16*)&u;
  return __bfloat162float(h);
}

__global__ __launch_bounds__(256) void prep_new(
    const float* __restrict__ w2_t, const float* __restrict__ w2_f,
    const float* __restrict__ w1_t, const float* __restrict__ w1_f,
    char* __restrict__ ws) {
  int idx = blockIdx.x * 256 + threadIdx.x;
  ushort* w2frag = (ushort*)(ws + W2B_OFF);
  float* w1t = (float*)(ws + W1T_OFF);
  if (idx < 294912) {
    int j    = idx & 7;
    int lane = (idx >> 3) & 63;
    int t2   = idx >> 9;          // [0,576)
    int kc   = t2 % 18;
    int t3   = t2 / 18;           // [0,32)
    int octile = t3 & 7;
    int t4   = t3 >> 3;           // [0,4)
    int e    = t4 & 1;
    int term = t4 >> 1;
    int oc = octile * 16 + (lane & 15);
    int kk = kc * 32 + (lane >> 4) * 8 + j;
    int kh = kk / 192, r2 = kk - kh * 192, kw = r2 >> 6, ic = r2 & 63;
    const float* src = e ? w2_f : w2_t;
    float w = src[((oc * 64 + ic) * 3 + kh) * 3 + kw];
    ushort hi = f2bf(w);
    w2frag[idx] = term ? f2bf(w - bf2f(hi)) : hi;
  } else if (idx < 294912 + 3456) {
    int i2 = idx - 294912;
    int e = i2 / 1728;
    int r = i2 - e * 1728;
    int k = r >> 6, ch = r & 63;
    const float* src = e ? w1_f : w1_t;
    w1t[i2] = src[ch * 27 + k];
  }
}

// conv1: block = 4 h1 rows (gR: rows 4gR..4gR+3) x BOTH experts (R7 version).
// Thread: chg=tid&7 (8 ch), pxg=(tid>>3)&15 (8 hx), rh=tid>>7 (2 rows each).
__global__ __launch_bounds__(256, 3) void conv1_cl(
    const float* __restrict__ x,
    const float* __restrict__ w1t_all,
    const float* __restrict__ b1_t, const float* __restrict__ b1_f,
    ushort* __restrict__ h1_all)
{
  const int gR  = blockIdx.x;   // 0..28
  const int b   = blockIdx.y;
  const int tid = threadIdx.x;

  __shared__ float x_s[3 * 9 * 232];   // [ic][xr_l][even 0..115 | odd 116..231]
  __shared__ float w1s[2 * 1728];      // [e][27 k][64 ch]

  for (int i = tid; i < 2 * 1728; i += 256) w1s[i] = w1t_all[i];

  const float* xb = x + (size_t)b * 150528;
  const int xr0 = 8 * gR;
  for (int i = tid; i < 3 * 9 * 113; i += 256) {
    int ic   = i / (9 * 113);
    int rem  = i - ic * (9 * 113);
    int xr_l = rem / 113;
    int col  = rem - xr_l * 113;
    int xr = xr0 + xr_l;
    float e0 = 0.f, o0 = 0.f;
    if (xr < 224 && col < 112) {
      const float2 p2 = *(const float2*)(xb + (ic * 224 + xr) * 224 + 2 * col);
      e0 = p2.x; o0 = p2.y;
    }
    x_s[(ic * 9 + xr_l) * 232 + col] = e0;
    x_s[(ic * 9 + xr_l) * 232 + 116 + col] = o0;
  }
  __syncthreads();

  const int chg = tid & 7;          // ch0 = chg*8
  const int pxg = (tid >> 3) & 15;  // hx0 = pxg*8
  const int rh  = tid >> 7;         // rows {2rh, 2rh+1} local
  const int hx0 = 8 * pxg;

  for (int e = 0; e < 2; ++e) {
    const float* w1sE = w1s + e * 1728;
    const float* b1 = e ? b1_f : b1_t;
    ushort* h1b = h1_all + (size_t)e * H1E_US + (size_t)b * H1B_US;
    const float4 bA = *(const float4*)&b1[chg * 8];
    const float4 bB = *(const float4*)&b1[chg * 8 + 4];
    const float bv[8] = {bA.x, bA.y, bA.z, bA.w, bB.x, bB.y, bB.z, bB.w};

    for (int rr = 0; rr < 2; ++rr) {
      const int rloc = 2 * rh + rr;
      const int row  = 4 * gR + rloc;
      if (row > 112) continue;
      const bool compute = (row < 112) && (pxg < 14);
      float acc[8][8];
#pragma unroll
      for (int c = 0; c < 8; ++c)
#pragma unroll
        for (int j = 0; j < 8; ++j) acc[c][j] = 0.f;

      if (compute) {
#pragma unroll
        for (int ickr = 0; ickr < 9; ++ickr) {
          const int ic = ickr / 3, kr = ickr - 3 * ic;
          const float* xs = &x_s[(ic * 9 + 2 * rloc + kr) * 232];
          float he[9], ho[8];
          *(float4*)&he[0] = *(const float4*)&xs[hx0];
          *(float4*)&he[4] = *(const float4*)&xs[hx0 + 4];
          he[8] = xs[hx0 + 8];
          *(float4*)&ho[0] = *(const float4*)&xs[116 + hx0];
          *(float4*)&ho[4] = *(const float4*)&xs[116 + hx0 + 4];
          const float4 wa0 = *(const float4*)&w1sE[(ickr * 3 + 0) * 64 + chg * 8];
          const float4 wa1 = *(const float4*)&w1sE[(ickr * 3 + 0) * 64 + chg * 8 + 4];
          const float4 wb0 = *(const float4*)&w1sE[(ickr * 3 + 1) * 64 + chg * 8];
          const float4 wb1 = *(const float4*)&w1sE[(ickr * 3 + 1) * 64 + chg * 8 + 4];
          const float4 wc0 = *(const float4*)&w1sE[(ickr * 3 + 2) * 64 + chg * 8];
          const float4 wc1 = *(const float4*)&w1sE[(ickr * 3 + 2) * 64 + chg * 8 + 4];
          const float wa[8] = {wa0.x, wa0.y, wa0.z, wa0.w, wa1.x, wa1.y, wa1.z, wa1.w};
          const float wb[8] = {wb0.x, wb0.y, wb0.z, wb0.w, wb1.x, wb1.y, wb1.z, wb1.w};
          const float wc[8] = {wc0.x, wc0.y, wc0.z, wc0.w, wc1.x, wc1.y, wc1.z, wc1.w};
#pragma unroll
          for (int j = 0; j < 8; ++j)
#pragma unroll
            for (int c = 0; c < 8; ++c) {
              acc[c][j] = fmaf(wa[c], he[j], acc[c][j]);
              acc[c][j] = fmaf(wb[c], ho[j], acc[c][j]);
              acc[c][j] = fmaf(wc[c], he[j + 1], acc[c][j]);
            }
        }
      }

#pragma unroll
      for (int j = 0; j < 8; ++j) {
        const int hx = hx0 + j;
        if (hx < 113) {
          const bool live = compute && (hx < 112);
          ushort v[8];
#pragma unroll
          for (int c = 0; c < 8; ++c)
            v[c] = f2bf(live ? fmaxf(acc[c][j] + bv[c], 0.f) : 0.f);
          uint4 u;
          u.x = (uint)v[0] | ((uint)v[1] << 16);
          u.y = (uint)v[2] | ((uint)v[3] << 16);
          u.z = (uint)v[4] | ((uint)v[5] << 16);
          u.w = (uint)v[6] | ((uint)v[7] << 16);
          *(uint4*)&h1b[((size_t)(row * 113 + hx)) * 64 + chg * 8] = u;
        }
      }
    }
  }
}

// conv2 via MFMA, LDS-free. Block (T=row-pair 0..27, b, e), 4 waves.
// Wave w: octiles {2w, 2w+1} (32 oc), 7 N-tiles (8px x 2rows = 112 px exact).
// B read directly from global h1 (16B/lane, q-lanes tile 64B sectors);
// A from w2frag (1KB coalesced per wave-load, L2-hot). Zero barriers.
__global__ __launch_bounds__(256) void conv2_mfma(
    const ushort* __restrict__ h1_all,
    const ushort* __restrict__ w2frag,
    const float* __restrict__ b2_t, const float* __restrict__ b2_f,
    float* __restrict__ g)
{
  const int T = blockIdx.x;
  const int b = blockIdx.y;
  const int e = blockIdx.z;
  const int tid  = threadIdx.x;
  const int w    = tid >> 6;
  const int lane = tid & 63;
  const ushort* h1b = h1_all + (size_t)e * H1E_US + (size_t)b * H1B_US;
  const float* b2 = e ? b2_f : b2_t;

  const int q   = lane >> 4;
  const int n   = lane & 15;
  const int pxl = lane & 7;
  const int rl  = (lane >> 3) & 1;

  f32x4 acc[2][7];
#pragma unroll
  for (int mt = 0; mt < 2; ++mt)
#pragma unroll
    for (int nt = 0; nt < 7; ++nt) acc[mt][nt] = (f32x4){0.f, 0.f, 0.f, 0.f};

  // A base pointers (per term/mt); kc stride = 512 ushorts
  const ushort* abase[2][2];
#pragma unroll
  for (int term = 0; term < 2; ++term)
#pragma unroll
    for (int mt = 0; mt < 2; ++mt)
      abase[term][mt] = w2frag
          + ((size_t)(((term * 2 + e) * 8 + 2 * w + mt) * 18)) * 512 + lane * 8;

#pragma unroll 1
  for (int kh = 0; kh < 3; ++kh) {
    const ushort* hrow = h1b + (size_t)((4 * T + kh + 2 * rl) * 113) * 64;
#pragma unroll 1
    for (int kw = 0; kw < 3; ++kw) {
#pragma unroll 1
      for (int icc = 0; icc < 2; ++icc) {
        const int kc = kh * 6 + kw * 2 + icc;
        const ushort* hp = hrow + (2 * pxl + kw) * 64 + icc * 32 + 8 * q;
        bf16x8 bfv[7];
#pragma unroll
        for (int nt = 0; nt < 7; ++nt)
          bfv[nt] = *(const bf16x8*)(hp + nt * 1024);
        bf16x8 af[2][2];
#pragma unroll
        for (int term = 0; term < 2; ++term)
#pragma unroll
          for (int mt = 0; mt < 2; ++mt)
            af[term][mt] = *(const bf16x8*)(abase[term][mt] + kc * 512);
#pragma unroll
        for (int term = 0; term < 2; ++term)
#pragma unroll
          for (int mt = 0; mt < 2; ++mt)
#pragma unroll
            for (int nt = 0; nt < 7; ++nt)
              acc[mt][nt] = __builtin_amdgcn_mfma_f32_16x16x32_bf16(
                  af[term][mt], bfv[nt], acc[mt][nt], 0, 0, 0);
      }
    }
  }

#pragma unroll
  for (int mt = 0; mt < 2; ++mt) {
#pragma unroll
    for (int reg = 0; reg < 4; ++reg) {
      const int oc = 32 * w + 16 * mt + 4 * q + reg;
      const float bias = b2[oc];
      float s = 0.f;
#pragma unroll
      for (int nt = 0; nt < 7; ++nt) s += fmaxf(acc[mt][nt][reg] + bias, 0.f);
      s += __shfl_xor(s, 1);
      s += __shfl_xor(s, 2);
      s += __shfl_xor(s, 4);
      s += __shfl_xor(s, 8);
      if (n == 0) atomicAdd(&g[((size_t)e * 64 + b) * 128 + oc], s);
    }
  }
}

__global__ __launch_bounds__(64) void finale(
    const float* __restrict__ g,
    const float* __restrict__ t_wf, const float* __restrict__ t_bf,
    const float* __restrict__ f_wf, const float* __restrict__ f_bf,
    float* __restrict__ out)
{
  const int b = threadIdx.x;
  const float inv = 1.0f / 3136.0f;
  const float* gt = g + b * 128;
  const float* gf = g + (64 + b) * 128;
  float lt0 = t_bf[0], lt1 = t_bf[1];
  float lf0 = f_bf[0], lf1 = f_bf[1];
  for (int k = 0; k < 128; ++k) {
    float vt = gt[k] * inv;
    float vf = gf[k] * inv;
    lt0 = fmaf(vt, t_wf[2 * k],     lt0);
    lt1 = fmaf(vt, t_wf[2 * k + 1], lt1);
    lf0 = fmaf(vf, f_wf[2 * k],     lf0);
    lf1 = fmaf(vf, f_wf[2 * k + 1], lf1);
  }
  float m  = fmaxf(lt0, lt1);
  float e0 = expf(lt0 - m), e1 = expf(lt1 - m);
  float conf = fmaxf(e0, e1) / (e0 + e1);
  bool use2 = (conf <= 0.9f);
  out[2 * b]     = use2 ? 0.7f * lt0 + 0.3f * lf0 : lt0;
  out[2 * b + 1] = use2 ? 0.7f * lt1 + 0.3f * lf1 : lt1;
  unsigned long long mask = __ballot(use2);
  if (b == 0) out[128] = (float)__popcll(mask) * (1.0f / 64.0f);
}

// ---------------- fallback (ws too small): round-1 fused fp32 ----------------
__global__ __launch_bounds__(256) void transpose_w2(
    const float* __restrict__ w2_t, const float* __restrict__ w2_f,
    float* __restrict__ w2t) {
  int idx = blockIdx.x * 256 + threadIdx.x;
  int e = idx / 73728;
  int r = idx - e * 73728;
  int k = r >> 7, oc = r & 127;
  const float* src = e ? w2_f : w2_t;
  w2t[idx] = src[oc * 576 + k];
}

__global__ __launch_bounds__(256, 3) void fused_expert(
    const float* __restrict__ x,
    const float* __restrict__ w1_t, const float* __restrict__ b1_t,
    const float* __restrict__ b2_t,
    const float* __restrict__ w1_f, const float* __restrict__ b1_f,
    const float* __restrict__ b2_f,
    const float* __restrict__ w2t_all, float* __restrict__ g)
{
  const int tile = blockIdx.x, b = blockIdx.y, e = blockIdx.z;
  const int ty = tile >> 1, tx = tile & 1;
  const float* w1  = e ? w1_f : w1_t;
  const float* b1  = e ? b1_f : b1_t;
  const float* b2  = e ? b2_f : b2_t;
  const float* w2t = w2t_all + e * 73728;
  __shared__ float x_s[3 * 19 * 116];
  __shared__ float h1_s[8 * 9 * 58];
  __shared__ float w1_s[1728];
  const int tid = threadIdx.x;
  {
    const float* xb = x + (size_t)b * 150528;
    const int xr0 = ty * 16, xc0 = tx * 112;
    for (int idx = tid; idx < 3 * 19 * 116; idx += 256) {
      int ic = idx / (19 * 116);
      int rem = idx - ic * (19 * 116);
      int r = rem / 116, cc = rem - r * 116;
      int xr = xr0 + r, xc = xc0 + cc;
      float v = 0.f;
      if (xr < 224 && xc < 224 && cc < 115) v = xb[(ic * 224 + xr) * 224 + xc];
      x_s[idx] = v;
    }
    for (int idx = tid; idx < 1728; idx += 256) w1_s[idx] = w1[idx];
  }
  const int ocg = tid >> 4, posg = tid & 15;
  int pbase[7];
#pragma unroll
  for (int j = 0; j < 7; ++j) {
    int p = posg + 16 * j, py = p / 28, px = p - py * 28;
    pbase[j] = py * 2 * 58 + px * 2;
  }
  float acc[7][8];
#pragma unroll
  for (int j = 0; j < 7; ++j)
#pragma unroll
    for (int i = 0; i < 8; ++i) acc[j][i] = 0.f;
  const int hc_l = tid >> 5, l32 = tid & 31;
  for (int c = 0; c < 8; ++c) {
    __syncthreads();
    {
      const int hc = c * 8 + hc_l;
      const float bias = b1[hc];
      float wr[27];
#pragma unroll
      for (int qq = 0; qq < 27; ++qq) wr[qq] = w1_s[hc * 27 + qq];
      for (int p = l32; p < 513; p += 32) {
        int hy = p / 57, hx = p - hy * 57;
        float a = bias;
#pragma unroll
        for (int ic = 0; ic < 3; ++ic)
#pragma unroll
          for (int kh = 0; kh < 3; ++kh) {
            const float* row = &x_s[ic * (19 * 116) + (2 * hy + kh) * 116 + 2 * hx];
            a = fmaf(row[0], wr[ic * 9 + kh * 3 + 0], a);
            a = fmaf(row[1], wr[ic * 9 + kh * 3 + 1], a);
            a = fmaf(row[2], wr[ic * 9 + kh * 3 + 2], a);
          }
        float v = fmaxf(a, 0.f);
        int hy_g = ty * 8 + hy, hx_g = tx * 56 + hx;
        if (hy_g >= 112 || hx_g >= 112) v = 0.f;
        h1_s[hc_l * 522 + hy * 58 + hx] = v;
      }
    }
    __syncthreads();
    for (int ic_l = 0; ic_l < 8; ++ic_l) {
#pragma unroll
      for (int kh = 0; kh < 3; ++kh)
#pragma unroll
        for (int kw = 0; kw < 3; ++kw) {
          const int k = (c * 8 + ic_l) * 9 + kh * 3 + kw;
          const float4 wA = *(const float4*)(w2t + k * 128 + ocg * 8);
          const float4 wB = *(const float4*)(w2t + k * 128 + ocg * 8 + 4);
          const float* hp = &h1_s[ic_l * 522 + kh * 58 + kw];
#pragma unroll
          for (int j = 0; j < 7; ++j) {
            float h = hp[pbase[j]];
            acc[j][0] = fmaf(wA.x, h, acc[j][0]);
            acc[j][1] = fmaf(wA.y, h, acc[j][1]);
            acc[j][2] = fmaf(wA.z, h, acc[j][2]);
            acc[j][3] = fmaf(wA.w, h, acc[j][3]);
            acc[j][4] = fmaf(wB.x, h, acc[j][4]);
            acc[j][5] = fmaf(wB.y, h, acc[j][5]);
            acc[j][6] = fmaf(wB.z, h, acc[j][6]);
            acc[j][7] = fmaf(wB.w, h, acc[j][7]);
          }
        }
    }
  }
  __syncthreads();
  float* red = x_s;
#pragma unroll
  for (int i = 0; i < 8; ++i) {
    float bb = b2[ocg * 8 + i];
    float t = 0.f;
#pragma unroll
    for (int j = 0; j < 7; ++j) t += fmaxf(acc[j][i] + bb, 0.f);
    red[posg * 129 + ocg * 8 + i] = t;
  }
  __syncthreads();
  if (tid < 128) {
    float t = 0.f;
#pragma unroll
    for (int pg = 0; pg < 16; ++pg) t += red[pg * 129 + tid];
    atomicAdd(&g[(e * 64 + b) * 128 + tid], t);
  }
}

extern "C" void kernel_launch(void* const* d_in, const int* in_sizes, int n_in,
                              void* d_out, int out_size, void* d_ws, size_t ws_size,
                              hipStream_t stream) {
  const float* x    = (const float*)d_in[0];
  const float* t_w1 = (const float*)d_in[1];
  const float* t_b1 = (const float*)d_in[2];
  const float* t_w2 = (const float*)d_in[3];
  const float* t_b2 = (const float*)d_in[4];
  const float* t_wf = (const float*)d_in[5];
  const float* t_bf = (const float*)d_in[6];
  const float* f_w1 = (const float*)d_in[7];
  const float* f_b1 = (const float*)d_in[8];
  const float* f_w2 = (const float*)d_in[9];
  const float* f_b2 = (const float*)d_in[10];
  const float* f_wf = (const float*)d_in[11];
  const float* f_bf = (const float*)d_in[12];
  float* out = (float*)d_out;
  char* ws = (char*)d_ws;

  if (ws_size >= WS_NEED) {
    float*  gbuf   = (float*)(ws + G_OFF);
    ushort* h1     = (ushort*)(ws + H1_OFF);
    ushort* w2frag = (ushort*)(ws + W2B_OFF);
    float*  w1t    = (float*)(ws + W1T_OFF);
    hipMemsetAsync(gbuf, 0, 2 * 64 * 128 * sizeof(float), stream);
    prep_new<<<1166, 256, 0, stream>>>(t_w2, f_w2, t_w1, f_w1, ws);
    conv1_cl<<<dim3(29, 64), 256, 0, stream>>>(x, w1t, t_b1, f_b1, h1);
    conv2_mfma<<<dim3(28, 64, 2), 256, 0, stream>>>(h1, w2frag, t_b2, f_b2, gbuf);
    finale<<<1, 64, 0, stream>>>(gbuf, t_wf, t_bf, f_wf, f_bf, out);
  } else {
    float* w2t = (float*)ws;
    float* g2  = (float*)(ws + 589824);
    hipMemsetAsync(g2, 0, 2 * 64 * 128 * sizeof(float), stream);
    transpose_w2<<<576, 256, 0, stream>>>(t_w2, f_w2, w2t);
    fused_expert<<<dim3(28, 64, 2), 256, 0, stream>>>(
        x, t_w1, t_b1, t_b2, f_w1, f_b1, f_b2, w2t, g2);
    finale<<<1, 64, 0, stream>>>(g2, t_wf, t_bf, f_wf, f_bf, out);
  }
}

// Round 10
// 361.716 us; speedup vs baseline: 1.4031x; 1.2808x over previous
//
#include <hip/hip_runtime.h>
#include <hip/hip_bf16.h>
#include <math.h>

// x [64,3,224,224] fp32; expert: conv3x3 s2 (3->64)+ReLU -> conv3x3 s2 (64->128)
// +ReLU -> GAP -> FC 128->2; blend on t softmax conf <= 0.9. Out: 129 floats.
// SAME s2: pad_lo=0, pad_hi=1 both convs.
//
// Round-10: known-good R7/R5 structure. conv2 single-term A (w2-hi only;
// error budget allows it). conv1 hx-split across 2 blocks (less LDS, more
// residency, smaller tail). g-zero folded into prep; finale vectorized.
//
// ws layout (bytes):
//   W2B_OFF: ushort w2frag[2 term][2 e][8 octile][18 kc][64 lane][8]
//            oc = octile*16 + (lane&15); kk = kc*32 + (lane>>4)*8 + j
//            kk = kh*192 + kw*64 + ic ; kc = kh*6 + kw*2 + icc   (term1 unused)
//   W1T_OFF: float  w1t[2 e][27 k][64 ch]   k = ic*9+kh*3+kw
//   G_OFF:   float  g[2 e][64 b][128 oc]
//   H1_OFF:  ushort h1[2 e][64 b][113 row][113 hx][64 ic] (row/col 112 = 0)

#define W2B_OFF   0ull
#define W1T_OFF   589824ull
#define G_OFF     603648ull
#define H1_OFF    669440ull
#define H1E_US    52301824ull   // 64*113*113*64
#define H1B_US    817216ull     // 113*113*64
#define WS_NEED   (H1_OFF + 2ull*H1E_US*2ull + 4096ull)

typedef __attribute__((ext_vector_type(8))) short bf16x8;
typedef __attribute__((ext_vector_type(4))) float f32x4;

__device__ inline ushort f2bf(float v) {
  __hip_bfloat16 h = __float2bfloat16(v);
  return *(ushort*)&h;
}
__device__ inline float bf2f(ushort u) {
  __hip_bfloat16 h = *(__hip_bfloat16*)&u;
  return __bfloat162float(h);
}

__global__ __launch_bounds__(256) void prep_new(
    const float* __restrict__ w2_t, const float* __restrict__ w2_f,
    const float* __restrict__ w1_t, const float* __restrict__ w1_f,
    char* __restrict__ ws) {
  int idx = blockIdx.x * 256 + threadIdx.x;
  ushort* w2frag = (ushort*)(ws + W2B_OFF);
  float* w1t = (float*)(ws + W1T_OFF);
  if (idx < 294912) {
    int j    = idx & 7;
    int lane = (idx >> 3) & 63;
    int t2   = idx >> 9;          // [0,576)
    int kc   = t2 % 18;
    int t3   = t2 / 18;           // [0,32)
    int octile = t3 & 7;
    int t4   = t3 >> 3;           // [0,4)
    int e    = t4 & 1;
    int term = t4 >> 1;
    int oc = octile * 16 + (lane & 15);
    int kk = kc * 32 + (lane >> 4) * 8 + j;
    int kh = kk / 192, r2 = kk - kh * 192, kw = r2 >> 6, ic = r2 & 63;
    const float* src = e ? w2_f : w2_t;
    float w = src[((oc * 64 + ic) * 3 + kh) * 3 + kw];
    ushort hi = f2bf(w);
    w2frag[idx] = term ? f2bf(w - bf2f(hi)) : hi;
  } else if (idx < 298368) {
    int i2 = idx - 294912;
    int e = i2 / 1728;
    int r = i2 - e * 1728;
    int k = r >> 6, ch = r & 63;
    const float* src = e ? w1_f : w1_t;
    w1t[i2] = src[ch * 27 + k];
  } else if (idx < 298368 + 16384) {
    ((float*)(ws + G_OFF))[idx - 298368] = 0.f;   // zero g (replaces memset)
  }
}

// conv1: block = (gR: 4 rows, hf: hx half, b). 256 thr = 8ch x 8px x 4rows.
// Thread: chg=tid&7 (ch chg*8..+7), pxg=(tid>>3)&7 (hx hf*64+pxg*8..+7),
// rh=tid>>6 (row 4gR+rh). x parity-split in LDS; both experts per block.
__global__ __launch_bounds__(256, 3) void conv1_cl(
    const float* __restrict__ x,
    const float* __restrict__ w1t_all,
    const float* __restrict__ b1_t, const float* __restrict__ b1_f,
    ushort* __restrict__ h1_all)
{
  const int gR = blockIdx.x;    // 0..28
  const int hf = blockIdx.y;    // 0..1
  const int b  = blockIdx.z;
  const int tid = threadIdx.x;

  __shared__ float x_s[3 * 9 * 136];   // [ic][xr_l][even 0..65 | odd 68..133]
  __shared__ float w1s[2 * 1728];      // [e][27 k][64 ch]

  for (int i = tid; i < 2 * 1728; i += 256) w1s[i] = w1t_all[i];

  const float* xb = x + (size_t)b * 150528;
  const int xr0 = 8 * gR;
  const int ce0 = hf * 64;
  for (int i = tid; i < 3 * 9 * 66; i += 256) {
    int ic   = i / (9 * 66);
    int rem  = i - ic * (9 * 66);
    int xr_l = rem / 66;
    int cl   = rem - xr_l * 66;
    int xr = xr0 + xr_l;
    int ce = ce0 + cl;
    float e0 = 0.f, o0 = 0.f;
    if (xr < 224 && ce < 112) {
      const float2 p2 = *(const float2*)(xb + (ic * 224 + xr) * 224 + 2 * ce);
      e0 = p2.x; o0 = p2.y;
    }
    x_s[(ic * 9 + xr_l) * 136 + cl] = e0;
    x_s[(ic * 9 + xr_l) * 136 + 68 + cl] = o0;
  }
  __syncthreads();

  const int chg = tid & 7;
  const int pxg = (tid >> 3) & 7;
  const int rh  = tid >> 6;         // 0..3
  const int pl  = 8 * pxg;
  const int row = 4 * gR + rh;
  if (row > 112) return;            // no barriers after this point
  const bool rowlive = row < 112;

  for (int e = 0; e < 2; ++e) {
    const float* w1sE = w1s + e * 1728;
    const float* b1 = e ? b1_f : b1_t;
    ushort* h1b = h1_all + (size_t)e * H1E_US + (size_t)b * H1B_US;
    const float4 bA = *(const float4*)&b1[chg * 8];
    const float4 bB = *(const float4*)&b1[chg * 8 + 4];
    const float bv[8] = {bA.x, bA.y, bA.z, bA.w, bB.x, bB.y, bB.z, bB.w};

    float acc[8][8];
#pragma unroll
    for (int c = 0; c < 8; ++c)
#pragma unroll
      for (int j = 0; j < 8; ++j) acc[c][j] = 0.f;

    if (rowlive) {
#pragma unroll
      for (int ickr = 0; ickr < 9; ++ickr) {
        const int ic = ickr / 3, kr = ickr - 3 * ic;
        const float* xs = &x_s[(ic * 9 + 2 * rh + kr) * 136];
        float he[9], ho[8];
        *(float4*)&he[0] = *(const float4*)&xs[pl];
        *(float4*)&he[4] = *(const float4*)&xs[pl + 4];
        he[8] = xs[pl + 8];
        *(float4*)&ho[0] = *(const float4*)&xs[68 + pl];
        *(float4*)&ho[4] = *(const float4*)&xs[68 + pl + 4];
        const float4 wa0 = *(const float4*)&w1sE[(ickr * 3 + 0) * 64 + chg * 8];
        const float4 wa1 = *(const float4*)&w1sE[(ickr * 3 + 0) * 64 + chg * 8 + 4];
        const float4 wb0 = *(const float4*)&w1sE[(ickr * 3 + 1) * 64 + chg * 8];
        const float4 wb1 = *(const float4*)&w1sE[(ickr * 3 + 1) * 64 + chg * 8 + 4];
        const float4 wc0 = *(const float4*)&w1sE[(ickr * 3 + 2) * 64 + chg * 8];
        const float4 wc1 = *(const float4*)&w1sE[(ickr * 3 + 2) * 64 + chg * 8 + 4];
        const float wa[8] = {wa0.x, wa0.y, wa0.z, wa0.w, wa1.x, wa1.y, wa1.z, wa1.w};
        const float wb[8] = {wb0.x, wb0.y, wb0.z, wb0.w, wb1.x, wb1.y, wb1.z, wb1.w};
        const float wc[8] = {wc0.x, wc0.y, wc0.z, wc0.w, wc1.x, wc1.y, wc1.z, wc1.w};
#pragma unroll
        for (int j = 0; j < 8; ++j)
#pragma unroll
          for (int c = 0; c < 8; ++c) {
            acc[c][j] = fmaf(wa[c], he[j], acc[c][j]);
            acc[c][j] = fmaf(wb[c], ho[j], acc[c][j]);
            acc[c][j] = fmaf(wc[c], he[j + 1], acc[c][j]);
          }
      }
    }

#pragma unroll
    for (int j = 0; j < 8; ++j) {
      const int hx = ce0 + pl + j;
      if (hx < 113) {
        const bool live = rowlive && (hx < 112);
        ushort v[8];
#pragma unroll
        for (int c = 0; c < 8; ++c)
          v[c] = f2bf(live ? fmaxf(acc[c][j] + bv[c], 0.f) : 0.f);
        uint4 u;
        u.x = (uint)v[0] | ((uint)v[1] << 16);
        u.y = (uint)v[2] | ((uint)v[3] << 16);
        u.z = (uint)v[4] | ((uint)v[5] << 16);
        u.w = (uint)v[6] | ((uint)v[7] << 16);
        *(uint4*)&h1b[((size_t)(row * 113 + hx)) * 64 + chg * 8] = u;
      }
    }
  }
}

// conv2 via MFMA (R5 structure, single A-term). Block (T 0..27, b, e), 4 waves.
// Wave w: octiles {2w, 2w+1} (32 oc), 7 N-tiles (8px x 2rows = 112 px exact).
__global__ __launch_bounds__(256) void conv2_mfma(
    const ushort* __restrict__ h1_all,
    const ushort* __restrict__ w2frag,
    const float* __restrict__ b2_t, const float* __restrict__ b2_f,
    float* __restrict__ g)
{
  const int T = blockIdx.x;
  const int b = blockIdx.y;
  const int e = blockIdx.z;
  const int tid  = threadIdx.x;
  const int w    = tid >> 6;
  const int lane = tid & 63;
  const ushort* h1b = h1_all + (size_t)e * H1E_US + (size_t)b * H1B_US;
  const float* b2 = e ? b2_f : b2_t;

  __shared__ ushort hs[2 * 113 * 72];   // 32.5 KB

  const int q   = lane >> 4;
  const int n   = lane & 15;
  const int pxl = lane & 7;
  const int rl  = (lane >> 3) & 1;

  f32x4 acc[2][7];
#pragma unroll
  for (int mt = 0; mt < 2; ++mt)
#pragma unroll
    for (int nt = 0; nt < 7; ++nt) acc[mt][nt] = (f32x4){0.f, 0.f, 0.f, 0.f};

  for (int kh = 0; kh < 3; ++kh) {
    __syncthreads();
    for (int i = tid; i < 1808; i += 256) {
      int rs = (i >= 904) ? 1 : 0;
      int rem = i - rs * 904;
      int hx = rem >> 3, gq = rem & 7;
      int R = 4 * T + kh + 2 * rs;
      *(bf16x8*)&hs[(rs * 113 + hx) * 72 + 8 * gq] =
          *(const bf16x8*)&h1b[((size_t)(R * 113 + hx)) * 64 + 8 * gq];
    }
    __syncthreads();
#pragma unroll
    for (int kw = 0; kw < 3; ++kw) {
#pragma unroll
      for (int icc = 0; icc < 2; ++icc) {
        const int kc = kh * 6 + kw * 2 + icc;
        const int icoff = icc * 32 + 8 * q;
        bf16x8 bfv[7];
#pragma unroll
        for (int nt = 0; nt < 7; ++nt) {
          int hx = 2 * (8 * nt + pxl) + kw;
          bfv[nt] = *(const bf16x8*)&hs[(rl * 113 + hx) * 72 + icoff];
        }
#pragma unroll
        for (int mt = 0; mt < 2; ++mt) {
          const int octile = 2 * w + mt;
          bf16x8 af = *(const bf16x8*)
              &w2frag[((size_t)((e * 8 + octile) * 18 + kc)) * 512 + lane * 8];
#pragma unroll
          for (int nt = 0; nt < 7; ++nt)
            acc[mt][nt] = __builtin_amdgcn_mfma_f32_16x16x32_bf16(
                af, bfv[nt], acc[mt][nt], 0, 0, 0);
        }
      }
    }
  }

#pragma unroll
  for (int mt = 0; mt < 2; ++mt) {
#pragma unroll
    for (int reg = 0; reg < 4; ++reg) {
      const int oc = 32 * w + 16 * mt + 4 * q + reg;
      const float bias = b2[oc];
      float s = 0.f;
#pragma unroll
      for (int nt = 0; nt < 7; ++nt) s += fmaxf(acc[mt][nt][reg] + bias, 0.f);
      s += __shfl_xor(s, 1);
      s += __shfl_xor(s, 2);
      s += __shfl_xor(s, 4);
      s += __shfl_xor(s, 8);
      if (n == 0) atomicAdd(&g[((size_t)e * 64 + b) * 128 + oc], s);
    }
  }
}

__global__ __launch_bounds__(64) void finale(
    const float* __restrict__ g,
    const float* __restrict__ t_wf, const float* __restrict__ t_bf,
    const float* __restrict__ f_wf, const float* __restrict__ f_bf,
    float* __restrict__ out)
{
  const int b = threadIdx.x;
  const float inv = 1.0f / 3136.0f;
  const float* gt = g + b * 128;
  const float* gf = g + (64 + b) * 128;
  float lt0 = t_bf[0], lt1 = t_bf[1];
  float lf0 = f_bf[0], lf1 = f_bf[1];
  for (int k = 0; k < 128; k += 4) {
    const float4 vt = *(const float4*)&gt[k];
    const float4 vf = *(const float4*)&gf[k];
    const float4 wt0 = *(const float4*)&t_wf[2 * k];
    const float4 wt1 = *(const float4*)&t_wf[2 * k + 4];
    const float4 wf0 = *(const float4*)&f_wf[2 * k];
    const float4 wf1 = *(const float4*)&f_wf[2 * k + 4];
    lt0 = fmaf(vt.x * inv, wt0.x, lt0); lt1 = fmaf(vt.x * inv, wt0.y, lt1);
    lt0 = fmaf(vt.y * inv, wt0.z, lt0); lt1 = fmaf(vt.y * inv, wt0.w, lt1);
    lt0 = fmaf(vt.z * inv, wt1.x, lt0); lt1 = fmaf(vt.z * inv, wt1.y, lt1);
    lt0 = fmaf(vt.w * inv, wt1.z, lt0); lt1 = fmaf(vt.w * inv, wt1.w, lt1);
    lf0 = fmaf(vf.x * inv, wf0.x, lf0); lf1 = fmaf(vf.x * inv, wf0.y, lf1);
    lf0 = fmaf(vf.y * inv, wf0.z, lf0); lf1 = fmaf(vf.y * inv, wf0.w, lf1);
    lf0 = fmaf(vf.z * inv, wf1.x, lf0); lf1 = fmaf(vf.z * inv, wf1.y, lf1);
    lf0 = fmaf(vf.w * inv, wf1.z, lf0); lf1 = fmaf(vf.w * inv, wf1.w, lf1);
  }
  float m  = fmaxf(lt0, lt1);
  float e0 = expf(lt0 - m), e1 = expf(lt1 - m);
  float conf = fmaxf(e0, e1) / (e0 + e1);
  bool use2 = (conf <= 0.9f);
  out[2 * b]     = use2 ? 0.7f * lt0 + 0.3f * lf0 : lt0;
  out[2 * b + 1] = use2 ? 0.7f * lt1 + 0.3f * lf1 : lt1;
  unsigned long long mask = __ballot(use2);
  if (b == 0) out[128] = (float)__popcll(mask) * (1.0f / 64.0f);
}

// ---------------- fallback (ws too small): round-1 fused fp32 ----------------
__global__ __launch_bounds__(256) void transpose_w2(
    const float* __restrict__ w2_t, const float* __restrict__ w2_f,
    float* __restrict__ w2t) {
  int idx = blockIdx.x * 256 + threadIdx.x;
  int e = idx / 73728;
  int r = idx - e * 73728;
  int k = r >> 7, oc = r & 127;
  const float* src = e ? w2_f : w2_t;
  w2t[idx] = src[oc * 576 + k];
}

__global__ __launch_bounds__(256, 3) void fused_expert(
    const float* __restrict__ x,
    const float* __restrict__ w1_t, const float* __restrict__ b1_t,
    const float* __restrict__ b2_t,
    const float* __restrict__ w1_f, const float* __restrict__ b1_f,
    const float* __restrict__ b2_f,
    const float* __restrict__ w2t_all, float* __restrict__ g)
{
  const int tile = blockIdx.x, b = blockIdx.y, e = blockIdx.z;
  const int ty = tile >> 1, tx = tile & 1;
  const float* w1  = e ? w1_f : w1_t;
  const float* b1  = e ? b1_f : b1_t;
  const float* b2  = e ? b2_f : b2_t;
  const float* w2t = w2t_all + e * 73728;
  __shared__ float x_s[3 * 19 * 116];
  __shared__ float h1_s[8 * 9 * 58];
  __shared__ float w1_s[1728];
  const int tid = threadIdx.x;
  {
    const float* xb = x + (size_t)b * 150528;
    const int xr0 = ty * 16, xc0 = tx * 112;
    for (int idx = tid; idx < 3 * 19 * 116; idx += 256) {
      int ic = idx / (19 * 116);
      int rem = idx - ic * (19 * 116);
      int r = rem / 116, cc = rem - r * 116;
      int xr = xr0 + r, xc = xc0 + cc;
      float v = 0.f;
      if (xr < 224 && xc < 224 && cc < 115) v = xb[(ic * 224 + xr) * 224 + xc];
      x_s[idx] = v;
    }
    for (int idx = tid; idx < 1728; idx += 256) w1_s[idx] = w1[idx];
  }
  const int ocg = tid >> 4, posg = tid & 15;
  int pbase[7];
#pragma unroll
  for (int j = 0; j < 7; ++j) {
    int p = posg + 16 * j, py = p / 28, px = p - py * 28;
    pbase[j] = py * 2 * 58 + px * 2;
  }
  float acc[7][8];
#pragma unroll
  for (int j = 0; j < 7; ++j)
#pragma unroll
    for (int i = 0; i < 8; ++i) acc[j][i] = 0.f;
  const int hc_l = tid >> 5, l32 = tid & 31;
  for (int c = 0; c < 8; ++c) {
    __syncthreads();
    {
      const int hc = c * 8 + hc_l;
      const float bias = b1[hc];
      float wr[27];
#pragma unroll
      for (int qq = 0; qq < 27; ++qq) wr[qq] = w1_s[hc * 27 + qq];
      for (int p = l32; p < 513; p += 32) {
        int hy = p / 57, hx = p - hy * 57;
        float a = bias;
#pragma unroll
        for (int ic = 0; ic < 3; ++ic)
#pragma unroll
          for (int kh = 0; kh < 3; ++kh) {
            const float* row = &x_s[ic * (19 * 116) + (2 * hy + kh) * 116 + 2 * hx];
            a = fmaf(row[0], wr[ic * 9 + kh * 3 + 0], a);
            a = fmaf(row[1], wr[ic * 9 + kh * 3 + 1], a);
            a = fmaf(row[2], wr[ic * 9 + kh * 3 + 2], a);
          }
        float v = fmaxf(a, 0.f);
        int hy_g = ty * 8 + hy, hx_g = tx * 56 + hx;
        if (hy_g >= 112 || hx_g >= 112) v = 0.f;
        h1_s[hc_l * 522 + hy * 58 + hx] = v;
      }
    }
    __syncthreads();
    for (int ic_l = 0; ic_l < 8; ++ic_l) {
#pragma unroll
      for (int kh = 0; kh < 3; ++kh)
#pragma unroll
        for (int kw = 0; kw < 3; ++kw) {
          const int k = (c * 8 + ic_l) * 9 + kh * 3 + kw;
          const float4 wA = *(const float4*)(w2t + k * 128 + ocg * 8);
          const float4 wB = *(const float4*)(w2t + k * 128 + ocg * 8 + 4);
          const float* hp = &h1_s[ic_l * 522 + kh * 58 + kw];
#pragma unroll
          for (int j = 0; j < 7; ++j) {
            float h = hp[pbase[j]];
            acc[j][0] = fmaf(wA.x, h, acc[j][0]);
            acc[j][1] = fmaf(wA.y, h, acc[j][1]);
            acc[j][2] = fmaf(wA.z, h, acc[j][2]);
            acc[j][3] = fmaf(wA.w, h, acc[j][3]);
            acc[j][4] = fmaf(wB.x, h, acc[j][4]);
            acc[j][5] = fmaf(wB.y, h, acc[j][5]);
            acc[j][6] = fmaf(wB.z, h, acc[j][6]);
            acc[j][7] = fmaf(wB.w, h, acc[j][7]);
          }
        }
    }
  }
  __syncthreads();
  float* red = x_s;
#pragma unroll
  for (int i = 0; i < 8; ++i) {
    float bb = b2[ocg * 8 + i];
    float t = 0.f;
#pragma unroll
    for (int j = 0; j < 7; ++j) t += fmaxf(acc[j][i] + bb, 0.f);
    red[posg * 129 + ocg * 8 + i] = t;
  }
  __syncthreads();
  if (tid < 128) {
    float t = 0.f;
#pragma unroll
    for (int pg = 0; pg < 16; ++pg) t += red[pg * 129 + tid];
    atomicAdd(&g[(e * 64 + b) * 128 + tid], t);
  }
}

extern "C" void kernel_launch(void* const* d_in, const int* in_sizes, int n_in,
                              void* d_out, int out_size, void* d_ws, size_t ws_size,
                              hipStream_t stream) {
  const float* x    = (const float*)d_in[0];
  const float* t_w1 = (const float*)d_in[1];
  const float* t_b1 = (const float*)d_in[2];
  const float* t_w2 = (const float*)d_in[3];
  const float* t_b2 = (const float*)d_in[4];
  const float* t_wf = (const float*)d_in[5];
  const float* t_bf = (const float*)d_in[6];
  const float* f_w1 = (const float*)d_in[7];
  const float* f_b1 = (const float*)d_in[8];
  const float* f_w2 = (const float*)d_in[9];
  const float* f_b2 = (const float*)d_in[10];
  const float* f_wf = (const float*)d_in[11];
  const float* f_bf = (const float*)d_in[12];
  float* out = (float*)d_out;
  char* ws = (char*)d_ws;

  if (ws_size >= WS_NEED) {
    float*  gbuf   = (float*)(ws + G_OFF);
    ushort* h1     = (ushort*)(ws + H1_OFF);
    ushort* w2frag = (ushort*)(ws + W2B_OFF);
    float*  w1t    = (float*)(ws + W1T_OFF);
    prep_new<<<1230, 256, 0, stream>>>(t_w2, f_w2, t_w1, f_w1, ws);
    conv1_cl<<<dim3(29, 2, 64), 256, 0, stream>>>(x, w1t, t_b1, f_b1, h1);
    conv2_mfma<<<dim3(28, 64, 2), 256, 0, stream>>>(h1, w2frag, t_b2, f_b2, gbuf);
    finale<<<1, 64, 0, stream>>>(gbuf, t_wf, t_bf, f_wf, f_bf, out);
  } else {
    float* w2t = (float*)ws;
    float* g2  = (float*)(ws + 589824);
    hipMemsetAsync(g2, 0, 2 * 64 * 128 * sizeof(float), stream);
    transpose_w2<<<576, 256, 0, stream>>>(t_w2, f_w2, w2t);
    fused_expert<<<dim3(28, 64, 2), 256, 0, stream>>>(
        x, t_w1, t_b1, t_b2, f_w1, f_b1, f_b2, w2t, g2);
    finale<<<1, 64, 0, stream>>>(g2, t_wf, t_bf, f_wf, f_bf, out);
  }
}